// Round 6
// baseline (109.938 us; speedup 1.0000x reference)
//
#include <hip/hip_runtime.h>

namespace {
constexpr int Sdim = 128;
constexpr int Tdim = 64;
constexpr int U2c  = 16;
constexpr int PT   = 32;                 // pixel locations per block (128B-contiguous yt rows)
constexpr int NTHREADS = 512;
constexpr int PP = Sdim * Sdim;          // 16384 pixels
constexpr int TQ = 16;                   // t-steps staged per phase (LDS = 32 KiB)
constexpr int NSTG = Tdim / TQ;          // 4 stages

typedef float floatx4 __attribute__((ext_vector_type(4)));   // native vec for nontemporal store
}

// (512,2): VGPR cap 256 -> compiler free (~120 live), no spill (R2 lesson: never clamp).
__global__ __launch_bounds__(NTHREADS, 2)
void upscale_fused(const float* __restrict__ yt,
                   const float* __restrict__ wgt,
                   const float* __restrict__ bias,
                   float* __restrict__ out)
{
    // layout [t_local][u][p ^ (2*t_local)]: XOR swizzle keeps staging writes <=4-way
    // and compute float2 reads conflict-free. 32 KiB, single-buffered: the T14 split
    // below keeps staging HBM latency out of the barrier-critical section.
    __shared__ float wlds[TQ * U2c * PT];

    const int tid   = threadIdx.x;
    const int p_blk = blockIdx.x * PT;

    const int pg = tid & 15;            // 2 pixels: p0, p0+1
    const int b2 = (tid >> 4) & 31;     // b in {b2, b2+32}
    const int p0 = p_blk + pg * 2;

    const float4* wgt4 = reinterpret_cast<const float4*>(wgt);

    // ---- T14 async-STAGE split: issue loads early, ds_write late -----------------
    float4 sreg[4];   // one stage's worth of weights in flight (+16 VGPR)
    auto stage_load = [&](int stg) {
        #pragma unroll
        for (int i = 0; i < 4; ++i) {
            const int f = i * NTHREADS + tid;    // 0..2047 float4s of the 32KB tile
            const int r = f >> 6;                // p row 0..31
            const int c = f & 63;                // float4 within the 1KB p-row
            sreg[i] = wgt4[(size_t)(p_blk + r) * 256 + (size_t)stg * 64 + c];
        }
    };
    auto stage_write = [&]() {
        #pragma unroll
        for (int i = 0; i < 4; ++i) {
            const int f = i * NTHREADS + tid;
            const int r = f >> 6;
            const int c = f & 63;
            const int tw = c >> 2;               // t_local 0..15
            const int uq = c & 3;                // u quad
            const int col = r ^ (2 * tw);
            float* dst = &wlds[(tw * U2c + uq * 4) * PT + col];
            dst[0 * PT] = sreg[i].x;  dst[1 * PT] = sreg[i].y;
            dst[2 * PT] = sreg[i].z;  dst[3 * PT] = sreg[i].w;
        }
    };

    stage_load(0);

    // ---- init acc with bias (identical for both b) -------------------------------
    float acc[2][2][16];   // [b][jp][u]
    #pragma unroll
    for (int jp = 0; jp < 2; ++jp) {
        const float* bp = bias + (size_t)(p0 + jp) * U2c;
        const float4 q0 = *reinterpret_cast<const float4*>(bp + 0);
        const float4 q1 = *reinterpret_cast<const float4*>(bp + 4);
        const float4 q2 = *reinterpret_cast<const float4*>(bp + 8);
        const float4 q3 = *reinterpret_cast<const float4*>(bp + 12);
        const float bb[16] = {q0.x,q0.y,q0.z,q0.w, q1.x,q1.y,q1.z,q1.w,
                              q2.x,q2.y,q2.z,q2.w, q3.x,q3.y,q3.z,q3.w};
        #pragma unroll
        for (int u = 0; u < 16; ++u) { acc[0][jp][u] = bb[u]; acc[1][jp][u] = bb[u]; }
    }

    // ---- yt: float2 per (b,t), no duplicate loads, wave = 4 x 128B segments ------
    const float* y0b = yt + (size_t)b2 * ((size_t)Tdim * PP) + p0;
    const float* y1b = y0b + (size_t)32 * Tdim * PP;
    auto ldy = [&](int t, float2& a, float2& b) {
        a = *reinterpret_cast<const float2*>(y0b + (size_t)t * PP);
        b = *reinterpret_cast<const float2*>(y1b + (size_t)t * PP);
    };

    auto step = [&](const float2& ya, const float2& yb, int tl) {
        const float* wrow = &wlds[tl * (U2c * PT) + ((pg * 2) ^ (2 * tl))];
        #pragma unroll
        for (int u = 0; u < 16; ++u) {
            const float2 wv = *reinterpret_cast<const float2*>(wrow + u * PT);
            acc[0][0][u] = fmaf(ya.x, wv.x, acc[0][0][u]);
            acc[0][1][u] = fmaf(ya.y, wv.y, acc[0][1][u]);
            acc[1][0][u] = fmaf(yb.x, wv.x, acc[1][0][u]);
            acc[1][1][u] = fmaf(yb.y, wv.y, acc[1][1][u]);
        }
    };

    // ---- depth-4 static ping-pong yt prefetch (no rotation moves) ----------------
    float2 A0, A1, B0, B1, C0, C1, D0, D1;
    ldy(0, A0, A1); ldy(1, B0, B1); ldy(2, C0, C1); ldy(3, D0, D1);

    stage_write();      // stage 0: write is in the prologue, nothing to hide under
    __syncthreads();    // stage 0 visible

    #pragma unroll 1
    for (int stg = 0; stg < NSTG; ++stg) {
        if (stg + 1 < NSTG) stage_load(stg + 1);   // HBM latency hides under compute

        #pragma unroll 1
        for (int tq = 0; tq < TQ; tq += 4) {
            const int tg = stg * TQ + tq;
            step(A0, A1, tq + 0); { const int tf = (tg + 4 < Tdim) ? tg + 4 : Tdim - 1; ldy(tf, A0, A1); }
            step(B0, B1, tq + 1); { const int tf = (tg + 5 < Tdim) ? tg + 5 : Tdim - 1; ldy(tf, B0, B1); }
            step(C0, C1, tq + 2); { const int tf = (tg + 6 < Tdim) ? tg + 6 : Tdim - 1; ldy(tf, C0, C1); }
            step(D0, D1, tq + 3); { const int tf = (tg + 7 < Tdim) ? tg + 7 : Tdim - 1; ldy(tf, D0, D1); }
        }

        if (stg + 1 < NSTG) {
            __syncthreads();    // all waves done reading current stage
            stage_write();      // regs -> LDS (loads returned long ago; cheap)
            __syncthreads();    // new stage visible
        }
    }

    // ---- epilogue: pixel-shuffle scatter, nontemporal (write-once) ---------------
    const int s1   = p_blk / Sdim;
    const int s2_0 = p_blk % Sdim;

    #pragma unroll
    for (int bi = 0; bi < 2; ++bi) {
        const int b = b2 + bi * 32;
        float* ob = out + (size_t)b * (512 * 512);
        #pragma unroll
        for (int jp = 0; jp < 2; ++jp) {
            const int c0 = (s2_0 + pg * 2 + jp) * 4;
            #pragma unroll
            for (int u1 = 0; u1 < 4; ++u1) {
                const int r = s1 * 4 + u1;
                floatx4 v;
                v.x = acc[bi][jp][u1 * 4 + 0];
                v.y = acc[bi][jp][u1 * 4 + 1];
                v.z = acc[bi][jp][u1 * 4 + 2];
                v.w = acc[bi][jp][u1 * 4 + 3];
                __builtin_nontemporal_store(v, reinterpret_cast<floatx4*>(ob + (size_t)r * 512 + c0));
            }
        }
    }
}

extern "C" void kernel_launch(void* const* d_in, const int* in_sizes, int n_in,
                              void* d_out, int out_size, void* d_ws, size_t ws_size,
                              hipStream_t stream)
{
    const float* yt   = (const float*)d_in[0];
    const float* wgt  = (const float*)d_in[1];
    const float* bias = (const float*)d_in[2];
    float* outp       = (float*)d_out;

    dim3 grid(PP / PT);     // 512 blocks
    dim3 block(NTHREADS);
    hipLaunchKernelGGL(upscale_fused, grid, block, 0, stream, yt, wgt, bias, outp);
}